// Round 14
// baseline (200.538 us; speedup 1.0000x reference)
//
#include <hip/hip_runtime.h>
#include <hip/hip_bf16.h>

// MAB block: Qp=Q@Wq+bq, Kp=K@Wk+bk, Vp=K@Wv+bv; 4-head masked attention
// (faithful torch mask bug: head h uses adj_mask[h] for ALL batches, since
// (h*B+b)//H == h when B==H==4); O = Qh + A@Vh; LN0; FFN residual; LN1.
// B=4, N=M=2048, D=128, H=4, dh=32.
//
// Scores tiny -> no-max softmax -> M-splits merge linearly.
// R14: attn q-tile halved to 16 rows -> grid 2048 (8 blocks/CU, double
// the latency-hiding pool; per-block VGPR/LDS halve). prep keeps R13's
// conflict-free untransposed W staging (6.2M->0 conflict cycles); epi
// keeps 512-thread blocks. Mask bit-words packed in prep registers
// before MFMA (67MB stream overlaps compute).
// Qb/Kb head-major. QK swapped (S^T). Opart head-major [sp][h][b][q][32]
// via LDS-transposed full-line stores. attn XCD-swizzled (combo=id&15).
// No aggressive launch_bounds (R5/R6's (256,4) forced VGPR=64 -> spills).
// Workspace ~20.6 MB (28.7 MB overflowed in R3).

typedef short bf16x8 __attribute__((ext_vector_type(8)));
typedef short bf16x4 __attribute__((ext_vector_type(4)));
typedef float f32x4 __attribute__((ext_vector_type(4)));

#define BN 4
#define SEQ 2048
#define DIM 128
#define NH 4
#define DH 32
#define ROWS (BN * SEQ)   // 8192
#define MS 4              // attention M-splits
#define MWORDS (SEQ / 32) // 64 mask words per row

static __device__ __forceinline__ unsigned short f2bf(float f) {
    __hip_bfloat16 h = __float2bfloat16(f);
    return *reinterpret_cast<unsigned short*>(&h);
}
static __device__ __forceinline__ float bf2f(unsigned short u) {
    union { unsigned int i; float f; } cv;
    cv.i = ((unsigned int)u) << 16;
    return cv.f;
}
static __device__ __forceinline__ unsigned int pack2bf(float a, float b) {
    return (unsigned int)f2bf(a) | ((unsigned int)f2bf(b) << 16);
}
static __device__ __forceinline__ unsigned int maskword(const int4* src) {
    unsigned int m = 0;
#pragma unroll
    for (int j = 0; j < 8; ++j) {
        int4 v = src[j];
        m |= (((unsigned)v.x & 1u) << (4 * j))
           | (((unsigned)v.y & 1u) << (4 * j + 1))
           | (((unsigned)v.z & 1u) << (4 * j + 2))
           | (((unsigned)v.w & 1u) << (4 * j + 3));
    }
    return m;
}

// ---------------------------------------------------------------- prep ----
// grid 1024. blocks 0..767: proj (proj=bx>>8, 32-row tile=bx&255), with the
// block's 8 mask rows reduced to registers BEFORE the MFMA section (stream
// overlaps compute). blocks 768..769: Wr1/Wr2 transpose + pack. 770..1023:
// pack only. bits[h][wd][q] written via LDS transpose (smem reuse).
__global__ __launch_bounds__(256) void proj_prep(
    const float* __restrict__ Q, const float* __restrict__ K,
    const float* __restrict__ bq, const float* __restrict__ bk,
    const float* __restrict__ bv,
    const float* __restrict__ Wq, const float* __restrict__ Wk,
    const float* __restrict__ Wv, const float* __restrict__ W1,
    const float* __restrict__ W2, const int* __restrict__ adj,
    float* __restrict__ Qp, unsigned short* __restrict__ Qb,
    unsigned short* __restrict__ Kb, unsigned short* __restrict__ Vt,
    unsigned short* __restrict__ WT, unsigned int* __restrict__ bits)
{
    __shared__ __align__(16) unsigned char smem[51264];
    const int bx = blockIdx.x;
    const int t = threadIdx.x;
    const int q0 = bx * 8;           // this block's 8 mask rows
    unsigned int packw[2];

    if (bx >= 768) {
        // pack words first (register-only; stream starts immediately)
#pragma unroll
        for (int i = 0; i < 2; ++i) {
            int widl = i * 256 + t;
            int ql = widl >> 6, wd = widl & 63;
            packw[i] = maskword((const int4*)(adj + (long)(q0 + ql) * SEQ + wd * 32));
        }
        if (bx < 770) {          // ---- FFN weight transpose (for epi) ----
            const float* W = (bx == 768) ? W1 : W2;
            unsigned short* out = WT + (bx - 768) * DIM * DIM;
            for (int i = t; i < DIM * DIM; i += 256) {
                int n = i >> 7, k = i & 127;
                out[i] = f2bf(W[k * DIM + n]);
            }
        }
    } else {
        // ---- projection ----
        // sW2[k][n] (UNTRANSPOSED, stride 132): writes contiguous, reads
        // scalar d16 pairs; both <=2-way on banks.
        unsigned short (*sW2)[132] = (unsigned short(*)[132])smem;           // 33792 B
        unsigned short (*sX)[136] = (unsigned short(*)[136])(smem + 33792);  //  8704 B
        unsigned short (*sY)[137] = (unsigned short(*)[137])(smem + 42496);  //  8768 B

        const int proj = bx >> 8;
        const int rowbase = (bx & 255) * 32;
        const float* X = (proj == 0) ? Q : K;
        const float* W = (proj == 0) ? Wq : (proj == 1) ? Wk : Wv;
        const float* bias = (proj == 0) ? bq : (proj == 1) ? bk : bv;
        const int bidx = rowbase >> 11;
        const int srowbase = rowbase & 2047;

        // stage W bf16 into LDS as-is: sW2[k][n]; contiguous uint2 writes
#pragma unroll
        for (int i = 0; i < 16; ++i) {
            int idx = i * 256 + t;
            int k = idx >> 5, n4 = (idx & 31) * 4;
            float4 v = *(const float4*)(W + k * DIM + n4);
            uint2 wv;
            wv.x = pack2bf(v.x, v.y);
            wv.y = pack2bf(v.z, v.w);
            *(uint2*)&sW2[k][n4] = wv;
        }
        // stage X tile as bf16
#pragma unroll
        for (int i = 0; i < 4; ++i) {
            int idx = i * 256 + t;
            int row = idx >> 5, c4 = (idx & 31) * 4;
            float4 v = *(const float4*)(X + (long)(rowbase + row) * DIM + c4);
            sX[row][c4 + 0] = f2bf(v.x);
            sX[row][c4 + 1] = f2bf(v.y);
            sX[row][c4 + 2] = f2bf(v.z);
            sX[row][c4 + 3] = f2bf(v.w);
        }
        // pack words now (register-only): 67MB stream overlaps MFMA below
#pragma unroll
        for (int i = 0; i < 2; ++i) {
            int widl = i * 256 + t;
            int ql = widl >> 6, wd = widl & 63;
            packw[i] = maskword((const int4*)(adj + (long)(q0 + ql) * SEQ + wd * 32));
        }
        __syncthreads();

        const int w = t >> 6, lane = t & 63;
        const int n16 = lane & 15, quad = lane >> 4;

        f32x4 acc[2][2];
#pragma unroll
        for (int r = 0; r < 2; ++r)
#pragma unroll
            for (int ct = 0; ct < 2; ++ct)
                acc[r][ct] = (f32x4){0.f, 0.f, 0.f, 0.f};

        for (int ks = 0; ks < 4; ++ks) {
            bf16x8 bfrag[2];
#pragma unroll
            for (int ct = 0; ct < 2; ++ct) {
                int ncol = w * 32 + ct * 16 + n16;
                bf16x8 bf;
#pragma unroll
                for (int j = 0; j < 8; ++j)
                    bf[j] = (short)sW2[ks * 32 + quad * 8 + j][ncol];
                bfrag[ct] = bf;
            }
#pragma unroll
            for (int r = 0; r < 2; ++r) {
                bf16x8 afrag = *(const bf16x8*)(&sX[r * 16 + n16][ks * 32 + quad * 8]);
#pragma unroll
                for (int ct = 0; ct < 2; ++ct)
                    acc[r][ct] = __builtin_amdgcn_mfma_f32_16x16x32_bf16(
                        afrag, bfrag[ct], acc[r][ct], 0, 0, 0);
            }
        }

#pragma unroll
        for (int r = 0; r < 2; ++r) {
#pragma unroll
            for (int ct = 0; ct < 2; ++ct) {
                int col = w * 32 + ct * 16 + n16;
                int hh = col >> 5, dd = col & 31;
                float bv_ = bias[col];
#pragma unroll
                for (int i = 0; i < 4; ++i) {
                    int lrow = r * 16 + quad * 4 + i;
                    int grow = rowbase + lrow;
                    int srow = srowbase + lrow;
                    float val = acc[r][ct][i] + bv_;
                    if (proj == 0) {
                        Qp[(long)grow * DIM + col] = val;
                        Qb[((long)(hh * BN + bidx) * SEQ + srow) * DH + dd]
                            = f2bf(val * 0.17677669529663687f);
                    } else if (proj == 1) {
                        Kb[((long)(hh * BN + bidx) * SEQ + srow) * DH + dd] = f2bf(val);
                    } else {
                        sY[lrow][col] = f2bf(val);
                    }
                }
            }
        }
        if (proj == 2) {
            __syncthreads();
#pragma unroll
            for (int i = 0; i < 16; ++i) {
                int idx = i * 256 + t;
                int c = idx >> 5, m = idx & 31;
                Vt[((long)bidx * DIM + c) * SEQ + srowbase + m] = sY[m][c];
            }
        }
    }
    __syncthreads();   // all smem reads done; reuse as sB

    // ---- bits store via LDS transpose: rows q0..q0+7 -> bits[h][wd][q] ----
    {
        unsigned int (*sB)[65] = (unsigned int(*)[65])smem;
#pragma unroll
        for (int i = 0; i < 2; ++i) {
            int widl = i * 256 + t;
            int ql = widl >> 6, wd = widl & 63;
            sB[ql][wd] = packw[i];
        }
        __syncthreads();
        const int h = q0 >> 11, qh0 = q0 & 2047;
#pragma unroll
        for (int i = 0; i < 2; ++i) {
            int idx = i * 256 + t;
            int wd = idx >> 3, ql = idx & 7;   // ql fastest -> coalesced chunks
            bits[((long)h * MWORDS + wd) * SEQ + qh0 + ql] = sB[ql][wd];
        }
    }
}

// ---------------------------------------------------------------- attn ----
// 1D grid 2048 (16-row q-tiles), XCD-swizzled: combo=id&15 -> (h,sp) pinned
// per XCD. wave = batch. Barrier-free; S^T QK; mask from 2MB L2-resident
// bits (broadcast dword per tile, prefetched); P via wave-private LDS;
// O partial written coalesced head-major [sp][h][b][q][32].
__global__ __launch_bounds__(256, 2) void attn_kernel(
    const unsigned short* __restrict__ Qb, const unsigned short* __restrict__ Kb,
    const unsigned short* __restrict__ Vt, const unsigned int* __restrict__ mbits,
    unsigned short* __restrict__ Opart, float* __restrict__ Lpart)
{
    __shared__ __align__(16) unsigned short sP[4][16][68];

    const int id = blockIdx.x;
    const int combo = id & 15;          // id%8 == combo%8 -> XCD-pinned
    const int qidx = id >> 4;           // 0..127
    const int h = combo >> 2;
    const int sp = combo & 3;
    const int qbase = qidx * 16;
    const int t = threadIdx.x;
    const int b = t >> 6;
    const int lane = t & 63, n16 = lane & 15, quad = lane >> 4;

    const unsigned short* Qh = Qb + ((long)(h * BN + b) * SEQ) * DH + quad * 8;
    const unsigned short* Kp = Kb + ((long)(h * BN + b) * SEQ) * DH + quad * 8;
    const unsigned short* Vp = Vt + ((long)b * DIM + h * DH) * SEQ + quad * 8;
    const unsigned int*   Mp = mbits + ((long)h * MWORDS + sp * 16) * SEQ + qbase + n16;

    bf16x8 qfrag = *(const bf16x8*)(Qh + (long)(qbase + n16) * DH);

    f32x4 o[2];
    float lsum = 0.f;
#pragma unroll
    for (int ct = 0; ct < 2; ++ct) o[ct] = (f32x4){0.f, 0.f, 0.f, 0.f};

    bf16x8 kf[2][2];
    unsigned int mw[2];
    const int mb0 = sp * 512;

#pragma unroll
    for (int c = 0; c < 2; ++c)
        kf[0][c] = *(const bf16x8*)(Kp + (long)(mb0 + c * 16 + n16) * DH);
    mw[0] = Mp[0];

    const f32x4 zero4 = {0.f, 0.f, 0.f, 0.f};

#pragma unroll
    for (int mt = 0; mt < 16; ++mt) {
        const int cur = mt & 1, nxt = cur ^ 1;
        const int mbc = mb0 + mt * 32;
        // V for the CURRENT tile (single-buffered; hidden by score chain)
        bf16x8 vf0 = *(const bf16x8*)(Vp + (long)(0 * 16 + n16) * SEQ + mbc);
        bf16x8 vf1 = *(const bf16x8*)(Vp + (long)(1 * 16 + n16) * SEQ + mbc);
        if (mt < 15) {
            const int mb = mbc + 32;
#pragma unroll
            for (int c = 0; c < 2; ++c)
                kf[nxt][c] = *(const bf16x8*)(Kp + (long)(mb + c * 16 + n16) * DH);
            mw[nxt] = Mp[(long)(mt + 1) * SEQ];
        }
        // S^T: mfma(kf, qf) -> lane holds S[q=n16][k=c*16+quad*4+i]
        f32x4 st[2];
#pragma unroll
        for (int c = 0; c < 2; ++c)
            st[c] = __builtin_amdgcn_mfma_f32_16x16x32_bf16(
                kf[cur][c], qfrag, zero4, 0, 0, 0);
        const unsigned int wm = mw[cur];
        float p[2][4];
#pragma unroll
        for (int c = 0; c < 2; ++c)
#pragma unroll
            for (int i = 0; i < 4; ++i) {
                float e = __expf(st[c][i]);
                p[c][i] = ((wm >> (c * 16 + quad * 4 + i)) & 1u) ? e : 0.f;
                lsum += p[c][i];
            }
#pragma unroll
        for (int c = 0; c < 2; ++c) {
            uint2 wv;
            wv.x = pack2bf(p[c][0], p[c][1]);
            wv.y = pack2bf(p[c][2], p[c][3]);
            *(uint2*)&sP[b][n16][c * 16 + quad * 4] = wv;
        }
        // PV (same-wave DS ordering makes writes visible)
        bf16x8 pa = *(const bf16x8*)(&sP[b][n16][quad * 8]);
        o[0] = __builtin_amdgcn_mfma_f32_16x16x32_bf16(pa, vf0, o[0], 0, 0, 0);
        o[1] = __builtin_amdgcn_mfma_f32_16x16x32_bf16(pa, vf1, o[1], 0, 0, 0);
    }

    // lsum: lane covers 8 k's for q-row n16; sum over the 4 quads
    lsum += __shfl_xor(lsum, 16, 64);
    lsum += __shfl_xor(lsum, 32, 64);

    // stash o into sP (free after last PV), then coalesced 1KB/wave store
#pragma unroll
    for (int ct = 0; ct < 2; ++ct)
#pragma unroll
        for (int i = 0; i < 4; ++i)
            sP[b][quad * 4 + i][ct * 16 + n16] = f2bf(o[ct][i]);
    {
        const uint4 w0 = *(const uint4*)&sP[b][lane >> 2][(lane & 3) * 8];
        unsigned short* Ob = Opart
            + ((((long)sp * NH + h) * BN + b) * SEQ + qbase) * 32;
        *(uint4*)(Ob + (long)lane * 8) = w0;
    }

    if (quad == 0)
        Lpart[(((long)sp * BN + b) * NH + h) * SEQ + qbase + n16] = lsum;
}

// ----------------------------------------------------------- epilogue ----
// 512 blocks x 512 threads, 16 rows per block: merge attn partials +
// residual -> LN0 -> FFN (2x MFMA GEMM + relu) -> residual -> LN1 -> out.
// 8 waves/block: wave w covers cols w*16..w*16+15 (one MFMA strip).
__global__ __launch_bounds__(512) void epi_kernel(
    const float* __restrict__ Qp, const unsigned short* __restrict__ Opart,
    const float* __restrict__ Lpart, const unsigned short* __restrict__ WT,
    const float* __restrict__ br1, const float* __restrict__ br2,
    const float* __restrict__ g0, const float* __restrict__ be0,
    const float* __restrict__ g1, const float* __restrict__ be1,
    float* __restrict__ out)
{
    __shared__ __align__(16) unsigned short sXb[16][136];
    __shared__ __align__(16) unsigned short sHb[16][136];
    __shared__ __align__(16) float sXf[16][132];

    const int rowbase = blockIdx.x * 16;
    const int t = threadIdx.x;
    const int row = t >> 5, col4 = (t & 31) * 4;
    const int grow = rowbase + row;
    const int bidx = grow >> 11;
    const int srow = grow & 2047;
    const int head = col4 >> 5;
    const int dd = col4 & 31;

    // merge attention partials (head-major layout), add Q residual, LN0
    {
        float l = 0.f;
#pragma unroll
        for (int s = 0; s < MS; ++s)
            l += Lpart[(((long)s * BN + bidx) * NH + head) * SEQ + srow];
        float linv = 1.f / l;

        float ovf[4];
#pragma unroll
        for (int j = 0; j < 4; ++j) ovf[j] = 0.f;
#pragma unroll
        for (int s = 0; s < MS; ++s) {
            bf16x4 p = *(const bf16x4*)(Opart
                + ((((long)s * NH + head) * BN + bidx) * SEQ + srow) * 32 + dd);
#pragma unroll
            for (int j = 0; j < 4; ++j) ovf[j] += bf2f((unsigned short)p[j]);
        }

        float vals[4];
        float sum = 0.f, ss = 0.f;
        {
            float4 qv = *(const float4*)(Qp + (long)grow * DIM + col4);
            vals[0] = qv.x + ovf[0] * linv;
            vals[1] = qv.y + ovf[1] * linv;
            vals[2] = qv.z + ovf[2] * linv;
            vals[3] = qv.w + ovf[3] * linv;
#pragma unroll
            for (int u = 0; u < 4; ++u) { sum += vals[u]; ss += vals[u] * vals[u]; }
        }
        sum += __shfl_xor(sum, 1, 32); sum += __shfl_xor(sum, 2, 32);
        sum += __shfl_xor(sum, 4, 32); sum += __shfl_xor(sum, 8, 32);
        sum += __shfl_xor(sum, 16, 32);
        ss  += __shfl_xor(ss, 1, 32);  ss  += __shfl_xor(ss, 2, 32);
        ss  += __shfl_xor(ss, 4, 32);  ss  += __shfl_xor(ss, 8, 32);
        ss  += __shfl_xor(ss, 16, 32);
        float mean = sum * (1.f / 128.f);
        float var  = ss * (1.f / 128.f) - mean * mean;
        float rstd = rsqrtf(var + 1e-5f);
#pragma unroll
        for (int j = 0; j < 4; ++j) {
            int col = col4 + j;
            float x = (vals[j] - mean) * rstd * g0[col] + be0[col];
            sXf[row][col] = x;
            sXb[row][col] = f2bf(x);
        }
    }
    __syncthreads();

    const int w = t >> 6, lane = t & 63;     // 8 waves
    const int n16 = lane & 15, quad = lane >> 4;
    const int col = w * 16 + n16;
    const unsigned short* W1t = WT;
    const unsigned short* W2t = WT + DIM * DIM;

    // GEMM1: hidden = relu(x @ W1 + br1)   (M=16, one 16-col strip per wave)
    f32x4 acc = (f32x4){0.f, 0.f, 0.f, 0.f};
    for (int ks = 0; ks < 4; ++ks) {
        bf16x8 afrag = *(const bf16x8*)(&sXb[n16][ks * 32 + quad * 8]);
        bf16x8 bfrag = *(const bf16x8*)(W1t + col * DIM + ks * 32 + quad * 8);
        acc = __builtin_amdgcn_mfma_f32_16x16x32_bf16(afrag, bfrag, acc, 0, 0, 0);
    }
    {
        float bb = br1[col];
#pragma unroll
        for (int i = 0; i < 4; ++i)
            sHb[quad * 4 + i][col] = f2bf(fmaxf(acc[i] + bb, 0.f));
    }
    __syncthreads();

    // GEMM2: y = x + hidden @ W2 + br2
    f32x4 acc2 = (f32x4){0.f, 0.f, 0.f, 0.f};
    for (int ks = 0; ks < 4; ++ks) {
        bf16x8 afrag = *(const bf16x8*)(&sHb[n16][ks * 32 + quad * 8]);
        bf16x8 bfrag = *(const bf16x8*)(W2t + col * DIM + ks * 32 + quad * 8);
        acc2 = __builtin_amdgcn_mfma_f32_16x16x32_bf16(afrag, bfrag, acc2, 0, 0, 0);
    }
    float yv[4];
    {
        float bb = br2[col];
#pragma unroll
        for (int i = 0; i < 4; ++i)
            yv[i] = acc2[i] + bb + sXf[quad * 4 + i][col];
    }
    __syncthreads();   // all sXf residual reads done
#pragma unroll
    for (int i = 0; i < 4; ++i)
        sXf[quad * 4 + i][col] = yv[i];
    __syncthreads();

    // LN1 + store
    {
        float vals[4];
        float sum = 0.f, ss = 0.f;
#pragma unroll
        for (int j = 0; j < 4; ++j) {
            float v = sXf[row][col4 + j];
            vals[j] = v; sum += v; ss += v * v;
        }
        sum += __shfl_xor(sum, 1, 32); sum += __shfl_xor(sum, 2, 32);
        sum += __shfl_xor(sum, 4, 32); sum += __shfl_xor(sum, 8, 32);
        sum += __shfl_xor(sum, 16, 32);
        ss  += __shfl_xor(ss, 1, 32);  ss  += __shfl_xor(ss, 2, 32);
        ss  += __shfl_xor(ss, 4, 32);  ss  += __shfl_xor(ss, 8, 32);
        ss  += __shfl_xor(ss, 16, 32);
        float mean = sum * (1.f / 128.f);
        float var  = ss * (1.f / 128.f) - mean * mean;
        float rstd = rsqrtf(var + 1e-5f);
        float4 ov;
        ov.x = (vals[0] - mean) * rstd * g1[col4 + 0] + be1[col4 + 0];
        ov.y = (vals[1] - mean) * rstd * g1[col4 + 1] + be1[col4 + 1];
        ov.z = (vals[2] - mean) * rstd * g1[col4 + 2] + be1[col4 + 2];
        ov.w = (vals[3] - mean) * rstd * g1[col4 + 3] + be1[col4 + 3];
        *(float4*)(out + (long)grow * DIM + col4) = ov;
    }
}

// --------------------------------------------------------------- launch ----
extern "C" void kernel_launch(void* const* d_in, const int* in_sizes, int n_in,
                              void* d_out, int out_size, void* d_ws, size_t ws_size,
                              hipStream_t stream) {
    const float* Q   = (const float*)d_in[0];
    const float* K   = (const float*)d_in[1];
    const int*   adj = (const int*)d_in[2];
    const float* Wq  = (const float*)d_in[3];
    const float* bq  = (const float*)d_in[4];
    const float* Wk  = (const float*)d_in[5];
    const float* bk  = (const float*)d_in[6];
    const float* Wv  = (const float*)d_in[7];
    const float* bv  = (const float*)d_in[8];
    const float* Wr1 = (const float*)d_in[9];
    const float* br1 = (const float*)d_in[10];
    const float* Wr2 = (const float*)d_in[11];
    const float* br2 = (const float*)d_in[12];
    const float* g0  = (const float*)d_in[13];
    const float* be0 = (const float*)d_in[14];
    const float* g1  = (const float*)d_in[15];
    const float* be1 = (const float*)d_in[16];
    float* out = (float*)d_out;

    // workspace carve (~20.6 MB; keep well under proven-safe 26.6 MB)
    float* Qp             = (float*)d_ws;                                    // 4 MB
    unsigned short* Opart = (unsigned short*)(Qp + (long)ROWS * DIM);        // 8 MB bf16
    float* Lpart          = (float*)(Opart + (long)MS * ROWS * DIM);         // 0.5 MB
    unsigned short* Qb    = (unsigned short*)(Lpart + (long)MS * BN * NH * SEQ);
    unsigned short* Kb    = Qb + (long)ROWS * DIM;
    unsigned short* Vt    = Kb + (long)ROWS * DIM;
    unsigned short* WT    = Vt + (long)ROWS * DIM;                 // 64 KB (W1t,W2t)
    unsigned int*   bits  = (unsigned int*)(WT + 2 * DIM * DIM);   // 2 MB

    proj_prep<<<1024, 256, 0, stream>>>(Q, K, bq, bk, bv, Wq, Wk, Wv, Wr1, Wr2,
                                        adj, Qp, Qb, Kb, Vt, WT, bits);
    attn_kernel<<<2048, 256, 0, stream>>>(Qb, Kb, Vt, bits, Opart, Lpart);
    epi_kernel<<<512, 512, 0, stream>>>(Qp, Opart, Lpart, WT, br1, br2,
                                        g0, be0, g1, be1, out);
}

// Round 15
// 172.622 us; speedup vs baseline: 1.1617x; 1.1617x over previous
//
#include <hip/hip_runtime.h>
#include <hip/hip_bf16.h>

// MAB block: Qp=Q@Wq+bq, Kp=K@Wk+bk, Vp=K@Wv+bv; 4-head masked attention
// (faithful torch mask bug: head h uses adj_mask[h] for ALL batches, since
// (h*B+b)//H == h when B==H==4); O = Qh + A@Vh; LN0; FFN residual; LN1.
// B=4, N=M=2048, D=128, H=4, dh=32.
//
// Scores tiny -> no-max softmax -> M-splits merge linearly.
// R15 = R13 (measured optimum, 174.3 us): proj W staged UNTRANSPOSED
// sW2[k][n] (contiguous writes conflict-free; transposed store was 32-way,
// 6.2M cycles), B-fragments via scalar d16 reads; mask bit-words packed in
// registers before the MFMA section (67MB stream overlaps compute); attn
// 32-row q-tiles grid 1024 (R14's 16-row tiles regressed: per-iteration
// fixed costs amortize over half the MFMA); epi 512-thread blocks.
// Qb/Kb head-major. QK swapped (S^T). Opart head-major [sp][h][b][q][32]
// via LDS-transposed full-line stores. attn XCD-swizzled (combo=id&15).
// No aggressive launch_bounds (R5/R6's (256,4) forced VGPR=64 -> spills).
// Workspace ~20.6 MB (28.7 MB overflowed in R3).

typedef short bf16x8 __attribute__((ext_vector_type(8)));
typedef short bf16x4 __attribute__((ext_vector_type(4)));
typedef float f32x4 __attribute__((ext_vector_type(4)));

#define BN 4
#define SEQ 2048
#define DIM 128
#define NH 4
#define DH 32
#define ROWS (BN * SEQ)   // 8192
#define MS 4              // attention M-splits
#define MWORDS (SEQ / 32) // 64 mask words per row

static __device__ __forceinline__ unsigned short f2bf(float f) {
    __hip_bfloat16 h = __float2bfloat16(f);
    return *reinterpret_cast<unsigned short*>(&h);
}
static __device__ __forceinline__ float bf2f(unsigned short u) {
    union { unsigned int i; float f; } cv;
    cv.i = ((unsigned int)u) << 16;
    return cv.f;
}
static __device__ __forceinline__ unsigned int pack2bf(float a, float b) {
    return (unsigned int)f2bf(a) | ((unsigned int)f2bf(b) << 16);
}
static __device__ __forceinline__ unsigned int maskword(const int4* src) {
    unsigned int m = 0;
#pragma unroll
    for (int j = 0; j < 8; ++j) {
        int4 v = src[j];
        m |= (((unsigned)v.x & 1u) << (4 * j))
           | (((unsigned)v.y & 1u) << (4 * j + 1))
           | (((unsigned)v.z & 1u) << (4 * j + 2))
           | (((unsigned)v.w & 1u) << (4 * j + 3));
    }
    return m;
}

// ---------------------------------------------------------------- prep ----
// grid 1024. blocks 0..767: proj (proj=bx>>8, 32-row tile=bx&255), with the
// block's 8 mask rows reduced to registers BEFORE the MFMA section (stream
// overlaps compute). blocks 768..769: Wr1/Wr2 transpose + pack. 770..1023:
// pack only. bits[h][wd][q] written via LDS transpose (smem reuse).
__global__ __launch_bounds__(256) void proj_prep(
    const float* __restrict__ Q, const float* __restrict__ K,
    const float* __restrict__ bq, const float* __restrict__ bk,
    const float* __restrict__ bv,
    const float* __restrict__ Wq, const float* __restrict__ Wk,
    const float* __restrict__ Wv, const float* __restrict__ W1,
    const float* __restrict__ W2, const int* __restrict__ adj,
    float* __restrict__ Qp, unsigned short* __restrict__ Qb,
    unsigned short* __restrict__ Kb, unsigned short* __restrict__ Vt,
    unsigned short* __restrict__ WT, unsigned int* __restrict__ bits)
{
    __shared__ __align__(16) unsigned char smem[51264];
    const int bx = blockIdx.x;
    const int t = threadIdx.x;
    const int q0 = bx * 8;           // this block's 8 mask rows
    unsigned int packw[2];

    if (bx >= 768) {
        // pack words first (register-only; stream starts immediately)
#pragma unroll
        for (int i = 0; i < 2; ++i) {
            int widl = i * 256 + t;
            int ql = widl >> 6, wd = widl & 63;
            packw[i] = maskword((const int4*)(adj + (long)(q0 + ql) * SEQ + wd * 32));
        }
        if (bx < 770) {          // ---- FFN weight transpose (for epi) ----
            const float* W = (bx == 768) ? W1 : W2;
            unsigned short* out = WT + (bx - 768) * DIM * DIM;
            for (int i = t; i < DIM * DIM; i += 256) {
                int n = i >> 7, k = i & 127;
                out[i] = f2bf(W[k * DIM + n]);
            }
        }
    } else {
        // ---- projection ----
        // sW2[k][n] (UNTRANSPOSED, stride 132): writes contiguous, reads
        // scalar d16 pairs; both <=2-way on banks.
        unsigned short (*sW2)[132] = (unsigned short(*)[132])smem;           // 33792 B
        unsigned short (*sX)[136] = (unsigned short(*)[136])(smem + 33792);  //  8704 B
        unsigned short (*sY)[137] = (unsigned short(*)[137])(smem + 42496);  //  8768 B

        const int proj = bx >> 8;
        const int rowbase = (bx & 255) * 32;
        const float* X = (proj == 0) ? Q : K;
        const float* W = (proj == 0) ? Wq : (proj == 1) ? Wk : Wv;
        const float* bias = (proj == 0) ? bq : (proj == 1) ? bk : bv;
        const int bidx = rowbase >> 11;
        const int srowbase = rowbase & 2047;

        // stage W bf16 into LDS as-is: sW2[k][n]; contiguous uint2 writes
#pragma unroll
        for (int i = 0; i < 16; ++i) {
            int idx = i * 256 + t;
            int k = idx >> 5, n4 = (idx & 31) * 4;
            float4 v = *(const float4*)(W + k * DIM + n4);
            uint2 wv;
            wv.x = pack2bf(v.x, v.y);
            wv.y = pack2bf(v.z, v.w);
            *(uint2*)&sW2[k][n4] = wv;
        }
        // stage X tile as bf16
#pragma unroll
        for (int i = 0; i < 4; ++i) {
            int idx = i * 256 + t;
            int row = idx >> 5, c4 = (idx & 31) * 4;
            float4 v = *(const float4*)(X + (long)(rowbase + row) * DIM + c4);
            sX[row][c4 + 0] = f2bf(v.x);
            sX[row][c4 + 1] = f2bf(v.y);
            sX[row][c4 + 2] = f2bf(v.z);
            sX[row][c4 + 3] = f2bf(v.w);
        }
        // pack words now (register-only): 67MB stream overlaps MFMA below
#pragma unroll
        for (int i = 0; i < 2; ++i) {
            int widl = i * 256 + t;
            int ql = widl >> 6, wd = widl & 63;
            packw[i] = maskword((const int4*)(adj + (long)(q0 + ql) * SEQ + wd * 32));
        }
        __syncthreads();

        const int w = t >> 6, lane = t & 63;
        const int n16 = lane & 15, quad = lane >> 4;

        f32x4 acc[2][2];
#pragma unroll
        for (int r = 0; r < 2; ++r)
#pragma unroll
            for (int ct = 0; ct < 2; ++ct)
                acc[r][ct] = (f32x4){0.f, 0.f, 0.f, 0.f};

        for (int ks = 0; ks < 4; ++ks) {
            bf16x8 bfrag[2];
#pragma unroll
            for (int ct = 0; ct < 2; ++ct) {
                int ncol = w * 32 + ct * 16 + n16;
                bf16x8 bf;
#pragma unroll
                for (int j = 0; j < 8; ++j)
                    bf[j] = (short)sW2[ks * 32 + quad * 8 + j][ncol];
                bfrag[ct] = bf;
            }
#pragma unroll
            for (int r = 0; r < 2; ++r) {
                bf16x8 afrag = *(const bf16x8*)(&sX[r * 16 + n16][ks * 32 + quad * 8]);
#pragma unroll
                for (int ct = 0; ct < 2; ++ct)
                    acc[r][ct] = __builtin_amdgcn_mfma_f32_16x16x32_bf16(
                        afrag, bfrag[ct], acc[r][ct], 0, 0, 0);
            }
        }

#pragma unroll
        for (int r = 0; r < 2; ++r) {
#pragma unroll
            for (int ct = 0; ct < 2; ++ct) {
                int col = w * 32 + ct * 16 + n16;
                int hh = col >> 5, dd = col & 31;
                float bv_ = bias[col];
#pragma unroll
                for (int i = 0; i < 4; ++i) {
                    int lrow = r * 16 + quad * 4 + i;
                    int grow = rowbase + lrow;
                    int srow = srowbase + lrow;
                    float val = acc[r][ct][i] + bv_;
                    if (proj == 0) {
                        Qp[(long)grow * DIM + col] = val;
                        Qb[((long)(hh * BN + bidx) * SEQ + srow) * DH + dd]
                            = f2bf(val * 0.17677669529663687f);
                    } else if (proj == 1) {
                        Kb[((long)(hh * BN + bidx) * SEQ + srow) * DH + dd] = f2bf(val);
                    } else {
                        sY[lrow][col] = f2bf(val);
                    }
                }
            }
        }
        if (proj == 2) {
            __syncthreads();
#pragma unroll
            for (int i = 0; i < 16; ++i) {
                int idx = i * 256 + t;
                int c = idx >> 5, m = idx & 31;
                Vt[((long)bidx * DIM + c) * SEQ + srowbase + m] = sY[m][c];
            }
        }
    }
    __syncthreads();   // all smem reads done; reuse as sB

    // ---- bits store via LDS transpose: rows q0..q0+7 -> bits[h][wd][q] ----
    {
        unsigned int (*sB)[65] = (unsigned int(*)[65])smem;
#pragma unroll
        for (int i = 0; i < 2; ++i) {
            int widl = i * 256 + t;
            int ql = widl >> 6, wd = widl & 63;
            sB[ql][wd] = packw[i];
        }
        __syncthreads();
        const int h = q0 >> 11, qh0 = q0 & 2047;
#pragma unroll
        for (int i = 0; i < 2; ++i) {
            int idx = i * 256 + t;
            int wd = idx >> 3, ql = idx & 7;   // ql fastest -> coalesced chunks
            bits[((long)h * MWORDS + wd) * SEQ + qh0 + ql] = sB[ql][wd];
        }
    }
}

// ---------------------------------------------------------------- attn ----
// 1D grid 1024, XCD-swizzled: combo=id&15 -> (h,sp) pinned per XCD.
// wave = batch. Barrier-free; S^T QK; mask from 2MB L2-resident bits
// (broadcast dword per (r,tile), prefetched one tile ahead); P via
// wave-private LDS; O partial written coalesced head-major [sp][h][b][q][32].
__global__ __launch_bounds__(256, 2) void attn_kernel(
    const unsigned short* __restrict__ Qb, const unsigned short* __restrict__ Kb,
    const unsigned short* __restrict__ Vt, const unsigned int* __restrict__ mbits,
    unsigned short* __restrict__ Opart, float* __restrict__ Lpart)
{
    __shared__ __align__(16) unsigned short sP[4][32][68];

    const int id = blockIdx.x;
    const int combo = id & 15;          // id%8 == combo%8 -> XCD-pinned
    const int qidx = id >> 4;
    const int h = combo >> 2;
    const int sp = combo & 3;
    const int qbase = qidx * 32;
    const int t = threadIdx.x;
    const int b = t >> 6;
    const int lane = t & 63, n16 = lane & 15, quad = lane >> 4;

    const unsigned short* Qh = Qb + ((long)(h * BN + b) * SEQ) * DH + quad * 8;
    const unsigned short* Kp = Kb + ((long)(h * BN + b) * SEQ) * DH + quad * 8;
    const unsigned short* Vp = Vt + ((long)b * DIM + h * DH) * SEQ + quad * 8;
    const unsigned int*   Mp = mbits + ((long)h * MWORDS + sp * 16) * SEQ + qbase + n16;

    bf16x8 qfrag[2];
#pragma unroll
    for (int r = 0; r < 2; ++r)
        qfrag[r] = *(const bf16x8*)(Qh + (long)(qbase + r * 16 + n16) * DH);

    f32x4 o[2][2];
    float lsum[2];
#pragma unroll
    for (int r = 0; r < 2; ++r) {
#pragma unroll
        for (int ct = 0; ct < 2; ++ct) o[r][ct] = (f32x4){0.f, 0.f, 0.f, 0.f};
        lsum[r] = 0.f;
    }

    bf16x8 kf[2][2];
    unsigned int mw[2][2];
    const int mb0 = sp * 512;

#pragma unroll
    for (int c = 0; c < 2; ++c)
        kf[0][c] = *(const bf16x8*)(Kp + (long)(mb0 + c * 16 + n16) * DH);
#pragma unroll
    for (int r = 0; r < 2; ++r) mw[0][r] = Mp[r * 16];

    const f32x4 zero4 = {0.f, 0.f, 0.f, 0.f};

#pragma unroll
    for (int mt = 0; mt < 16; ++mt) {
        const int cur = mt & 1, nxt = cur ^ 1;
        const int mbc = mb0 + mt * 32;
        bf16x8 vf0 = *(const bf16x8*)(Vp + (long)(0 * 16 + n16) * SEQ + mbc);
        bf16x8 vf1 = *(const bf16x8*)(Vp + (long)(1 * 16 + n16) * SEQ + mbc);
        if (mt < 15) {
            const int mb = mbc + 32;
#pragma unroll
            for (int c = 0; c < 2; ++c)
                kf[nxt][c] = *(const bf16x8*)(Kp + (long)(mb + c * 16 + n16) * DH);
#pragma unroll
            for (int r = 0; r < 2; ++r) mw[nxt][r] = Mp[(long)(mt + 1) * SEQ + r * 16];
        }
#pragma unroll
        for (int r = 0; r < 2; ++r) {
            f32x4 st[2];
#pragma unroll
            for (int c = 0; c < 2; ++c)
                st[c] = __builtin_amdgcn_mfma_f32_16x16x32_bf16(
                    kf[cur][c], qfrag[r], zero4, 0, 0, 0);
            const unsigned int wm = mw[cur][r];
            float p[2][4];
#pragma unroll
            for (int c = 0; c < 2; ++c)
#pragma unroll
                for (int i = 0; i < 4; ++i) {
                    float e = __expf(st[c][i]);
                    p[c][i] = ((wm >> (c * 16 + quad * 4 + i)) & 1u) ? e : 0.f;
                    lsum[r] += p[c][i];
                }
#pragma unroll
            for (int c = 0; c < 2; ++c) {
                uint2 wv;
                wv.x = pack2bf(p[c][0], p[c][1]);
                wv.y = pack2bf(p[c][2], p[c][3]);
                *(uint2*)&sP[b][r * 16 + n16][c * 16 + quad * 4] = wv;
            }
        }
#pragma unroll
        for (int r = 0; r < 2; ++r) {
            bf16x8 pa = *(const bf16x8*)(&sP[b][r * 16 + n16][quad * 8]);
            o[r][0] = __builtin_amdgcn_mfma_f32_16x16x32_bf16(pa, vf0, o[r][0], 0, 0, 0);
            o[r][1] = __builtin_amdgcn_mfma_f32_16x16x32_bf16(pa, vf1, o[r][1], 0, 0, 0);
        }
    }

#pragma unroll
    for (int r = 0; r < 2; ++r) {
        lsum[r] += __shfl_xor(lsum[r], 16, 64);
        lsum[r] += __shfl_xor(lsum[r], 32, 64);
    }

    // stash o into sP (free after last PV), then coalesced 2KB/wave store
#pragma unroll
    for (int r = 0; r < 2; ++r)
#pragma unroll
        for (int ct = 0; ct < 2; ++ct)
#pragma unroll
            for (int i = 0; i < 4; ++i)
                sP[b][r * 16 + quad * 4 + i][ct * 16 + n16] = f2bf(o[r][ct][i]);
    {
        const uint4 w0 = *(const uint4*)&sP[b][lane >> 1][(lane & 1) * 16];
        const uint4 w1 = *(const uint4*)&sP[b][lane >> 1][(lane & 1) * 16 + 8];
        unsigned short* Ob = Opart
            + ((((long)sp * NH + h) * BN + b) * SEQ + qbase) * 32;
        *(uint4*)(Ob + (long)lane * 16)     = w0;
        *(uint4*)(Ob + (long)lane * 16 + 8) = w1;
    }

    if (quad == 0) {
#pragma unroll
        for (int r = 0; r < 2; ++r)
            Lpart[(((long)sp * BN + b) * NH + h) * SEQ + qbase + r * 16 + n16] = lsum[r];
    }
}

// ----------------------------------------------------------- epilogue ----
// 512 blocks x 512 threads, 16 rows per block: merge attn partials +
// residual -> LN0 -> FFN (2x MFMA GEMM + relu) -> residual -> LN1 -> out.
// 8 waves/block: wave w covers cols w*16..w*16+15 (one MFMA strip).
__global__ __launch_bounds__(512) void epi_kernel(
    const float* __restrict__ Qp, const unsigned short* __restrict__ Opart,
    const float* __restrict__ Lpart, const unsigned short* __restrict__ WT,
    const float* __restrict__ br1, const float* __restrict__ br2,
    const float* __restrict__ g0, const float* __restrict__ be0,
    const float* __restrict__ g1, const float* __restrict__ be1,
    float* __restrict__ out)
{
    __shared__ __align__(16) unsigned short sXb[16][136];
    __shared__ __align__(16) unsigned short sHb[16][136];
    __shared__ __align__(16) float sXf[16][132];

    const int rowbase = blockIdx.x * 16;
    const int t = threadIdx.x;
    const int row = t >> 5, col4 = (t & 31) * 4;
    const int grow = rowbase + row;
    const int bidx = grow >> 11;
    const int srow = grow & 2047;
    const int head = col4 >> 5;
    const int dd = col4 & 31;

    // merge attention partials (head-major layout), add Q residual, LN0
    {
        float l = 0.f;
#pragma unroll
        for (int s = 0; s < MS; ++s)
            l += Lpart[(((long)s * BN + bidx) * NH + head) * SEQ + srow];
        float linv = 1.f / l;

        float ovf[4];
#pragma unroll
        for (int j = 0; j < 4; ++j) ovf[j] = 0.f;
#pragma unroll
        for (int s = 0; s < MS; ++s) {
            bf16x4 p = *(const bf16x4*)(Opart
                + ((((long)s * NH + head) * BN + bidx) * SEQ + srow) * 32 + dd);
#pragma unroll
            for (int j = 0; j < 4; ++j) ovf[j] += bf2f((unsigned short)p[j]);
        }

        float vals[4];
        float sum = 0.f, ss = 0.f;
        {
            float4 qv = *(const float4*)(Qp + (long)grow * DIM + col4);
            vals[0] = qv.x + ovf[0] * linv;
            vals[1] = qv.y + ovf[1] * linv;
            vals[2] = qv.z + ovf[2] * linv;
            vals[3] = qv.w + ovf[3] * linv;
#pragma unroll
            for (int u = 0; u < 4; ++u) { sum += vals[u]; ss += vals[u] * vals[u]; }
        }
        sum += __shfl_xor(sum, 1, 32); sum += __shfl_xor(sum, 2, 32);
        sum += __shfl_xor(sum, 4, 32); sum += __shfl_xor(sum, 8, 32);
        sum += __shfl_xor(sum, 16, 32);
        ss  += __shfl_xor(ss, 1, 32);  ss  += __shfl_xor(ss, 2, 32);
        ss  += __shfl_xor(ss, 4, 32);  ss  += __shfl_xor(ss, 8, 32);
        ss  += __shfl_xor(ss, 16, 32);
        float mean = sum * (1.f / 128.f);
        float var  = ss * (1.f / 128.f) - mean * mean;
        float rstd = rsqrtf(var + 1e-5f);
#pragma unroll
        for (int j = 0; j < 4; ++j) {
            int col = col4 + j;
            float x = (vals[j] - mean) * rstd * g0[col] + be0[col];
            sXf[row][col] = x;
            sXb[row][col] = f2bf(x);
        }
    }
    __syncthreads();

    const int w = t >> 6, lane = t & 63;     // 8 waves
    const int n16 = lane & 15, quad = lane >> 4;
    const int col = w * 16 + n16;
    const unsigned short* W1t = WT;
    const unsigned short* W2t = WT + DIM * DIM;

    // GEMM1: hidden = relu(x @ W1 + br1)   (M=16, one 16-col strip per wave)
    f32x4 acc = (f32x4){0.f, 0.f, 0.f, 0.f};
    for (int ks = 0; ks < 4; ++ks) {
        bf16x8 afrag = *(const bf16x8*)(&sXb[n16][ks * 32 + quad * 8]);
        bf16x8 bfrag = *(const bf16x8*)(W1t + col * DIM + ks * 32 + quad * 8);
        acc = __builtin_amdgcn_mfma_f32_16x16x32_bf16(afrag, bfrag, acc, 0, 0, 0);
    }
    {
        float bb = br1[col];
#pragma unroll
        for (int i = 0; i < 4; ++i)
            sHb[quad * 4 + i][col] = f2bf(fmaxf(acc[i] + bb, 0.f));
    }
    __syncthreads();

    // GEMM2: y = x + hidden @ W2 + br2
    f32x4 acc2 = (f32x4){0.f, 0.f, 0.f, 0.f};
    for (int ks = 0; ks < 4; ++ks) {
        bf16x8 afrag = *(const bf16x8*)(&sHb[n16][ks * 32 + quad * 8]);
        bf16x8 bfrag = *(const bf16x8*)(W2t + col * DIM + ks * 32 + quad * 8);
        acc2 = __builtin_amdgcn_mfma_f32_16x16x32_bf16(afrag, bfrag, acc2, 0, 0, 0);
    }
    float yv[4];
    {
        float bb = br2[col];
#pragma unroll
        for (int i = 0; i < 4; ++i)
            yv[i] = acc2[i] + bb + sXf[quad * 4 + i][col];
    }
    __syncthreads();   // all sXf residual reads done
#pragma unroll
    for (int i = 0; i < 4; ++i)
        sXf[quad * 4 + i][col] = yv[i];
    __syncthreads();

    // LN1 + store
    {
        float vals[4];
        float sum = 0.f, ss = 0.f;
#pragma unroll
        for (int j = 0; j < 4; ++j) {
            float v = sXf[row][col4 + j];
            vals[j] = v; sum += v; ss += v * v;
        }
        sum += __shfl_xor(sum, 1, 32); sum += __shfl_xor(sum, 2, 32);
        sum += __shfl_xor(sum, 4, 32); sum += __shfl_xor(sum, 8, 32);
        sum += __shfl_xor(sum, 16, 32);
        ss  += __shfl_xor(ss, 1, 32);  ss  += __shfl_xor(ss, 2, 32);
        ss  += __shfl_xor(ss, 4, 32);  ss  += __shfl_xor(ss, 8, 32);
        ss  += __shfl_xor(ss, 16, 32);
        float mean = sum * (1.f / 128.f);
        float var  = ss * (1.f / 128.f) - mean * mean;
        float rstd = rsqrtf(var + 1e-5f);
        float4 ov;
        ov.x = (vals[0] - mean) * rstd * g1[col4 + 0] + be1[col4 + 0];
        ov.y = (vals[1] - mean) * rstd * g1[col4 + 1] + be1[col4 + 1];
        ov.z = (vals[2] - mean) * rstd * g1[col4 + 2] + be1[col4 + 2];
        ov.w = (vals[3] - mean) * rstd * g1[col4 + 3] + be1[col4 + 3];
        *(float4*)(out + (long)grow * DIM + col4) = ov;
    }
}

// --------------------------------------------------------------- launch ----
extern "C" void kernel_launch(void* const* d_in, const int* in_sizes, int n_in,
                              void* d_out, int out_size, void* d_ws, size_t ws_size,
                              hipStream_t stream) {
    const float* Q   = (const float*)d_in[0];
    const float* K   = (const float*)d_in[1];
    const int*   adj = (const int*)d_in[2];
    const float* Wq  = (const float*)d_in[3];
    const float* bq  = (const float*)d_in[4];
    const float* Wk  = (const float*)d_in[5];
    const float* bk  = (const float*)d_in[6];
    const float* Wv  = (const float*)d_in[7];
    const float* bv  = (const float*)d_in[8];
    const float* Wr1 = (const float*)d_in[9];
    const float* br1 = (const float*)d_in[10];
    const float* Wr2 = (const float*)d_in[11];
    const float* br2 = (const float*)d_in[12];
    const float* g0  = (const float*)d_in[13];
    const float* be0 = (const float*)d_in[14];
    const float* g1  = (const float*)d_in[15];
    const float* be1 = (const float*)d_in[16];
    float* out = (float*)d_out;

    // workspace carve (~20.6 MB; keep well under proven-safe 26.6 MB)
    float* Qp             = (float*)d_ws;                                    // 4 MB
    unsigned short* Opart = (unsigned short*)(Qp + (long)ROWS * DIM);        // 8 MB bf16
    float* Lpart          = (float*)(Opart + (long)MS * ROWS * DIM);         // 0.5 MB
    unsigned short* Qb    = (unsigned short*)(Lpart + (long)MS * BN * NH * SEQ);
    unsigned short* Kb    = Qb + (long)ROWS * DIM;
    unsigned short* Vt    = Kb + (long)ROWS * DIM;
    unsigned short* WT    = Vt + (long)ROWS * DIM;                 // 64 KB (W1t,W2t)
    unsigned int*   bits  = (unsigned int*)(WT + 2 * DIM * DIM);   // 2 MB

    proj_prep<<<1024, 256, 0, stream>>>(Q, K, bq, bk, bv, Wq, Wk, Wv, Wr1, Wr2,
                                        adj, Qp, Qb, Kb, Vt, WT, bits);
    attn_kernel<<<1024, 256, 0, stream>>>(Qb, Kb, Vt, bits, Opart, Lpart);
    epi_kernel<<<512, 512, 0, stream>>>(Qp, Opart, Lpart, WT, br1, br2,
                                        g0, be0, g1, be1, out);
}